// Round 6
// baseline (2151.736 us; speedup 1.0000x reference)
//
#include <hip/hip_runtime.h>
#include <stdint.h>

#define BATCH 8
#define K 65536
#define CFEAT 128
#define NPROP 1024
#define M 16            // workgroups per batch
#define T 256           // threads per WG
#define PTS (K / M)     // 4096 points per WG
#define PPT (PTS / T)   // 16 points per thread

// d_out layout (float32): new_xyz (B,N,3) | new_features (B,C,N) | inds (B,N) as float
#define OUT_FEAT (BATCH * NPROP * 3)                         // 24576
#define OUT_INDS (BATCH * NPROP * 3 + BATCH * CFEAT * NPROP) // 1073152

// ws layout: slot[2][BATCH][M] lines, each padded to its OWN 64B cacheline.
// KEY-ONLY protocol (round-3 validated: 2782->1972us): word [0] =
// key { dist_u32 | (0xFFFF-g)<<16 | tag }.
// All spin-path accesses RELAXED agent-scope (acquire emits buffer_inv ->
// chip-wide L2 thrash, round-2 lesson). Exact 16-bit tag + parity
// double-buffer: a WG posts round t only after finishing its poll of round
// t-1, which requires every WG posted t-1, which requires every WG finished
// polling t-2 (the same-parity round) — so overwrite races are impossible.
// (Bail-early via s_done preserves this: s_done==t is only set by a wave
// that fully detected round t, and bailing waves still precede S2.)
#define SLOT_STRIDE 8
#define WS_ULLS (2 * BATCH * M * SLOT_STRIDE)   // 2048 ulls = 16 KB

__global__ __launch_bounds__(256) void fps_init(unsigned long long* ws) {
    int i = blockIdx.x * 256 + threadIdx.x;
    if (i < WS_ULLS) ws[i] = 0ull;   // tag 0 never matches t in [1,1023]
}

// Wave-wide u32 max via DPP (HW-validated rounds 2-4). Max lands in lane 63.
__device__ __forceinline__ unsigned int wave_umax63(unsigned int x) {
    int v = (int)x;
    int t;
    t = __builtin_amdgcn_update_dpp(v, v, 0x111, 0xF, 0xF, false);  // row_shr:1
    v = ((unsigned)t > (unsigned)v) ? t : v;
    t = __builtin_amdgcn_update_dpp(v, v, 0x112, 0xF, 0xF, false);  // row_shr:2
    v = ((unsigned)t > (unsigned)v) ? t : v;
    t = __builtin_amdgcn_update_dpp(v, v, 0x114, 0xF, 0xF, false);  // row_shr:4
    v = ((unsigned)t > (unsigned)v) ? t : v;
    t = __builtin_amdgcn_update_dpp(v, v, 0x118, 0xF, 0xF, false);  // row_shr:8
    v = ((unsigned)t > (unsigned)v) ? t : v;
    t = __builtin_amdgcn_update_dpp(v, v, 0x142, 0xF, 0xF, false);  // row_bcast:15
    v = ((unsigned)t > (unsigned)v) ? t : v;
    t = __builtin_amdgcn_update_dpp(v, v, 0x143, 0xF, 0xF, false);  // row_bcast:31
    v = ((unsigned)t > (unsigned)v) ? t : v;
    return (unsigned int)v;
}

// 16-lane (row 0) u32 max via DPP; max of lanes 0..15 lands in lane 15.
__device__ __forceinline__ unsigned int row16_umax15(unsigned int x) {
    int v = (int)x;
    int t;
    t = __builtin_amdgcn_update_dpp(v, v, 0x111, 0xF, 0xF, false);  // row_shr:1
    v = ((unsigned)t > (unsigned)v) ? t : v;
    t = __builtin_amdgcn_update_dpp(v, v, 0x112, 0xF, 0xF, false);  // row_shr:2
    v = ((unsigned)t > (unsigned)v) ? t : v;
    t = __builtin_amdgcn_update_dpp(v, v, 0x114, 0xF, 0xF, false);  // row_shr:4
    v = ((unsigned)t > (unsigned)v) ? t : v;
    t = __builtin_amdgcn_update_dpp(v, v, 0x118, 0xF, 0xF, false);  // row_shr:8
    v = ((unsigned)t > (unsigned)v) ? t : v;
    return (unsigned int)v;
}

__global__ __launch_bounds__(T) void fps_kernel(const float* __restrict__ xyz,
                                                float* __restrict__ out,
                                                unsigned long long* __restrict__ ws) {
    const int b = blockIdx.x & 7;   // batch's 16 WGs round-robin onto one XCD
    const int w = blockIdx.x >> 3;
    const int tid = threadIdx.x;
    const int lane = tid & 63;
    const int wv = tid >> 6;
    const float* xb = xyz + (size_t)b * (K * 3);
    const int base = w * PTS;

    __shared__ unsigned long long s_wkey[T / 64];
    __shared__ int s_g;
    __shared__ int s_done;   // tag of the last fully-detected round

    float px[PPT], py[PPT], pz[PPT], dist[PPT];
#pragma unroll
    for (int j = 0; j < PPT; ++j) {
        int l = j * T + tid;
        int g = base + l;
        px[j] = xb[3 * g];
        py[j] = xb[3 * g + 1];
        pz[j] = xb[3 * g + 2];
        dist[j] = 1e10f;
    }
    float qx = xb[0], qy = xb[1], qz = xb[2];
    if (tid == 0) s_done = 0;
    if (w == 0 && tid == 0) out[OUT_INDS + b * NPROP] = 0.0f;

    for (int t = 1; t < NPROP; ++t) {
        // ---- local distance update + per-lane argmax (bit-exact vs numpy:
        // no FMA contraction, (dx2+dy2)+dz2 order, first-max tie-break via
        // strict > over ascending l) ----
        float bestd = -1.0f;
        unsigned int bestl = 0;
#pragma unroll
        for (int j = 0; j < PPT; ++j) {
            float dx = __fsub_rn(px[j], qx);
            float dy = __fsub_rn(py[j], qy);
            float dz = __fsub_rn(pz[j], qz);
            float d = __fadd_rn(__fadd_rn(__fmul_rn(dx, dx), __fmul_rn(dy, dy)),
                                __fmul_rn(dz, dz));
            float nd = fminf(dist[j], d);
            dist[j] = nd;
            unsigned int l = (unsigned int)(j * T + tid);
            bool gt = nd > bestd;
            bestd = gt ? nd : bestd;
            bestl = gt ? l : bestl;
        }
        // ---- wave-level two-phase argmax via DPP (dist >= 0 so float order
        // == u32 bit order; phase2 max(~l) == first-max tie-break) ----
        unsigned int du = __float_as_uint(bestd);
        unsigned int m1 = wave_umax63(du);
        unsigned int maxd = (unsigned int)__builtin_amdgcn_readlane((int)m1, 63);
        unsigned int cand = (du == maxd) ? ~bestl : 0u;
        unsigned int m2 = wave_umax63(cand);

        const int par = t & 1;
        unsigned long long* sgrp = ws + (size_t)((par * BATCH + b) * M) * SLOT_STRIDE;
        const unsigned int tt = (unsigned int)t;

        if (lane == 63) {
            unsigned int l = ~m2;                 // wave-winner local index
            unsigned int g = (unsigned int)base + l;
            s_wkey[wv] = ((unsigned long long)maxd << 32) |
                         ((unsigned long long)((0xFFFFu - g) & 0xFFFFu) << 16) |
                         (unsigned long long)tt;
        }
        __syncthreads();   // S1

        // ---- two polling waves (wv 0,1; lanes 0..15 each), PHASE-OFFSET by
        // s_sleep so the combined sampling grid has period ~L/2: a dependent
        // spin samples once per fabric RTT L, and one wave's 16 lanes all
        // sample in phase, so a second offset clock is the only way to halve
        // detection overshoot. Dependent spins leave no in-flight loads at
        // exit (no vmcnt-drain tax at S2). First wave to fully detect
        // publishes s_g and s_done=t; the other bails via s_done. ----
        if (wv <= 1 && lane < M) {
            // wave-parallel cross-wave key scan (replaces tid0 serial scan)
            unsigned long long kb = s_wkey[0];
#pragma unroll
            for (int i = 1; i < T / 64; ++i) kb = (s_wkey[i] > kb) ? s_wkey[i] : kb;
            if (tid == 0)
                __hip_atomic_store(&sgrp[(size_t)w * SLOT_STRIDE], kb,
                                   __ATOMIC_RELAXED, __HIP_MEMORY_SCOPE_AGENT);
            if (wv == 1) __builtin_amdgcn_s_sleep(6);   // ~384 cy phase offset
            unsigned long long k = kb;    // own-slot bypass: no fabric RTT
            bool have = true;
            if (lane != w) {
                have = false; k = 0ull;
                unsigned long long* sp = sgrp + (size_t)lane * SLOT_STRIDE;
                for (;;) {
                    unsigned long long v = __hip_atomic_load(
                        sp, __ATOMIC_RELAXED, __HIP_MEMORY_SCOPE_AGENT);
                    if ((unsigned short)v == (unsigned short)tt) { k = v; have = true; break; }
                    if (__hip_atomic_load(&s_done, __ATOMIC_RELAXED,
                                          __HIP_MEMORY_SCOPE_WORKGROUP) == t) break;
                }
            }
            unsigned long long miss = __ballot(!have);
            if (miss == 0ull) {
                // this wave has all 16 keys: two-phase argmax via DPP
                unsigned int hi = (unsigned int)(k >> 32);
                unsigned int lo = (unsigned int)k;
                unsigned int p1 = row16_umax15(hi);
                unsigned int maxk = (unsigned int)__builtin_amdgcn_readlane((int)p1, 15);
                unsigned int c2 = (hi == maxk) ? lo : 0u;   // (0xFFFF-g)<<16 | t
                unsigned int p2 = row16_umax15(c2);
                unsigned int low = (unsigned int)__builtin_amdgcn_readlane((int)p2, 15);
                unsigned int g = 0xFFFFu - (low >> 16);
                if (lane == 0) {
                    s_g = (int)g;   // double-write from both waves is benign (same value)
                    if (w == 0) out[OUT_INDS + b * NPROP + t] = (float)g;
                    __hip_atomic_store(&s_done, t, __ATOMIC_RELAXED,
                                       __HIP_MEMORY_SCOPE_WORKGROUP);
                }
            }
        }
        __syncthreads();   // S2
        // winner coords re-fetched from immutable input (same-address
        // broadcast, XCD-L2 resident: batch xyz = 768 KB streamed through
        // this XCD's L2 at init)
        int g = s_g;
        qx = xb[3 * g];
        qy = xb[3 * g + 1];
        qz = xb[3 * g + 2];
    }
}

__global__ __launch_bounds__(256) void gather_kernel(const float* __restrict__ xyz,
                                                     const float* __restrict__ feat,
                                                     float* __restrict__ out) {
    int gid = blockIdx.x * 256 + threadIdx.x;   // covers B*C*N = 1,048,576
    int n = gid & (NPROP - 1);
    int b = gid >> 17;                          // C*N = 2^17
    int c = (gid >> 10) & (CFEAT - 1);
    int ind = (int)out[OUT_INDS + (b << 10) + n];   // float inds, exact < 2^24
    out[OUT_FEAT + gid] = feat[(((size_t)b * CFEAT + c) << 16) + (size_t)ind];
    if (gid < BATCH * NPROP) {
        int b2 = gid >> 10;
        int ind2 = (int)out[OUT_INDS + gid];
        const float* s = xyz + ((size_t)b2 * K + (size_t)ind2) * 3;
        float a0 = s[0], a1 = s[1], a2 = s[2];
        out[gid * 3 + 0] = a0;
        out[gid * 3 + 1] = a1;
        out[gid * 3 + 2] = a2;
    }
}

extern "C" void kernel_launch(void* const* d_in, const int* in_sizes, int n_in,
                              void* d_out, int out_size, void* d_ws, size_t ws_size,
                              hipStream_t stream) {
    const float* xyz = (const float*)d_in[0];
    const float* feat = (const float*)d_in[1];
    float* out = (float*)d_out;
    unsigned long long* ws = (unsigned long long*)d_ws;

    hipLaunchKernelGGL(fps_init, dim3(WS_ULLS / 256), dim3(256), 0, stream, ws);
    hipLaunchKernelGGL(fps_kernel, dim3(BATCH * M), dim3(T), 0, stream,
                       xyz, out, ws);
    hipLaunchKernelGGL(gather_kernel, dim3(BATCH * CFEAT * NPROP / 256), dim3(256),
                       0, stream, xyz, feat, out);
}